// Round 4
// baseline (1514.561 us; speedup 1.0000x reference)
//
#include <hip/hip_runtime.h>

// MyRNN: B=128, T=80, E=100, V=10000, U=512
// 8 clusters x 32 member-blocks, formed DYNAMICALLY by physical XCD
// (s_getreg HW_REG_XCC_ID + atomic slot grab): with 156KB LDS -> 1 block/CU,
// grid 256 fills all CUs, so each XCD hosts exactly 32 blocks -> a cluster's
// members share one L2 BY CONSTRUCTION (G16-sound, no mapping assumption).
// Cluster c owns batch rows [16c,16c+16); member m owns cols [16m,16m+16) of
// rk0/rk1/k1 (stationary in LDS, hi/lo bf16 split).
// R1-R6: protocol variants on MALL data path pinned at 5.5-7us/exchange.
// R7 (745us): data path on XCD L2 (plain stores + sc0 dwordx4 gathers);
//   protocol on MALL single atomic counter.
// R9 (588us): per-member MALL flag words -> parallel posts, wave-par poll.
// R8/R10 post-mortem (hang / +1.8us/exchange = L2-spin timeout): plain
//   fire-and-forget stores to a hot flag word are NOT promptly visible to
//   sc0 polls (pre-L2 commit lag). sc0 loads DO bypass L1 (proven by R7-R9
//   gather correctness across 80 steps). Break is store-side.
// R11: L2 fast path rebuilt on ATOMICS end-to-end (atomics execute at the
//   XCD L2 when sc1 is absent; ack == L2 execution, no WC-buffer lag):
//   - data writes:  global_atomic_swap (no return) -> ack => in L2;
//   - post:         vmcnt(0) then global_atomic_swap round id to L2 flag,
//                   mirrored to the R9 MALL flag (fallback);
//   - poll (w0 only; barrier releases w1): bounded 48-iter spin of
//                   global_atomic_or dst,addr,0 sc0 (atomic read at L2),
//                   then fall back to the R9-proven MALL spin -> termination
//                   by construction, graceful degradation if no-sc1 atomics
//                   route to MALL (degenerates into exactly R9's spin).
//   - replay hygiene: prologue atomic-swap-zero of own L2 flag (overwrites
//     stale dirty line from prior replay) + MALL rendezvous on a separate
//     memset-zeroed word before first poll; end-of-kernel __threadfence.
//   Flag value = round id (2t+1 after h0, 2t+2 after h1): monotonic.

typedef __attribute__((ext_vector_type(8))) short short8;
typedef __attribute__((ext_vector_type(4))) float f32x4;

#define MFMA16(a,b,c) __builtin_amdgcn_mfma_f32_16x16x32_bf16(a,b,c,0,0,0)
#define LOAD_RLX(p)    __hip_atomic_load((p), __ATOMIC_RELAXED, __HIP_MEMORY_SCOPE_AGENT)
#define STORE_RLX(p,v) __hip_atomic_store((p), (v), __ATOMIC_RELAXED, __HIP_MEMORY_SCOPE_AGENT)
#define ADD_RLX(p,v)   __hip_atomic_fetch_add((p), (v), __ATOMIC_RELAXED, __HIP_MEMORY_SCOPE_AGENT)

__device__ __forceinline__ short f2bf(float v){
  unsigned u = __float_as_uint(v);
  u = (u + 0x7fffu + ((u >> 16) & 1u)) >> 16;   // RNE to bf16
  return (short)u;
}
__device__ __forceinline__ float bf2f(short s){
  return __uint_as_float(((unsigned)(unsigned short)s) << 16);
}
__device__ __forceinline__ float fast_tanh(float x){
  x = fminf(15.f, fmaxf(-15.f, x));
  float e = __expf(2.f * x);
  return (e - 1.f) * __builtin_amdgcn_rcpf(e + 1.f);
}

__launch_bounds__(128, 1)
__global__ void rnn_kernel(const int* __restrict__ tokens,
                           const float* __restrict__ emb,
                           const float* __restrict__ k0,
                           const float* __restrict__ rk0,
                           const float* __restrict__ b0,
                           const float* __restrict__ k1,
                           const float* __restrict__ rk1,
                           const float* __restrict__ b1,
                           const float* __restrict__ wd,
                           const float* __restrict__ bd,
                           float* __restrict__ out,
                           char* __restrict__ ws)
{
  constexpr int T = 80, E = 100, U = 512;
  const int tid  = threadIdx.x;
  const int w    = tid >> 6;          // wave id (0/1)
  const int lane = tid & 63;
  const int m    = lane & 15;         // row (A) / col (B,C)
  const int q    = lane >> 4;         // quad 0..3

  __shared__ __align__(16) short sW[6][16][520];   // rk0 hi/lo, rk1 hi/lo, k1 hi/lo : [col][k]
  __shared__ __align__(16) short sH[2][16][520];   // h / h0 staging hi,lo : [row][k]
  __shared__ __align__(16) short sE[2][16][136];   // emb rows hi,lo (K padded to 128 w/ zeros)
  __shared__ __align__(16) short sK0[2][16][136];  // k0 slice hi,lo : [col][k] (padded)
  __shared__ int   sTok[16][80];
  __shared__ float sB0[16], sB1[16];
  __shared__ float sRed[16][8];
  __shared__ int   sReg[2];

  // ws layout (all flag regions < 16384 = memset span; data at 16384):
  int*      regCnt = (int*)(ws + 512);             // 8 registration counters, 64B stride (MALL)
  int*      flagsL = (int*)(ws + 1024);            // 256 L2-atomic round flags, 16B stride
  int*      flagsR = (int*)(ws + 5120);            // 256 MALL rendezvous words, 8B stride
  int*      flagsM = (int*)(ws + 8192);            // 256 MALL round flags, 32B stride (R9)
  unsigned* hPk    = (unsigned*)(ws + 16*1024);    // h1 packed (hi<<16|lo), [128][512]
  unsigned* h0Pk   = hPk + 128*U;                  // h0 packed

  // -------- dynamic cluster formation: cluster id = physical XCD --------
  int xcc;
  asm volatile("s_getreg_b32 %0, hwreg(HW_REG_XCC_ID)" : "=s"(xcc));
  if (tid == 0){
    int slot = ADD_RLX(regCnt + (xcc & 7)*16, 1);  // 0..31 within this XCD
    sReg[0] = xcc & 7;
    sReg[1] = slot;
  }
  __syncthreads();
  const int cl  = sReg[0];
  const int mem = sReg[1];
  int* const myFlagL   = flagsL + (cl*32 + mem)*4;
  int* const myFlagR   = flagsR + (cl*32 + mem)*2;
  int* const myFlagM   = flagsM + (cl*32 + mem)*8;
  int* const pollAddrL = flagsL + (cl*32 + (lane & 31))*4;
  int* const pollAddrR = flagsR + (cl*32 + (lane & 31))*2;
  int* const pollAddrM = flagsM + (cl*32 + (lane & 31))*8;

  // ---------------- prologue: stationary weights -> LDS ----------------
  const float* mats[3] = { rk0, rk1, k1 };
  for (int mi = 0; mi < 3; ++mi){
    const float* G = mats[mi];
    for (int i = tid; i < 16*U; i += 128){
      int k = i >> 4, c = i & 15;
      float v  = G[k*U + mem*16 + c];
      short hi = f2bf(v);
      short lo = f2bf(v - bf2f(hi));
      sW[2*mi+0][c][k] = hi;
      sW[2*mi+1][c][k] = lo;
    }
  }
  for (int i = tid; i < 2*16*136; i += 128){ ((short*)sE)[i] = 0; ((short*)sK0)[i] = 0; }
  __syncthreads();
  for (int i = tid; i < 16*E; i += 128){
    int e = i >> 4, c = i & 15;
    float v  = k0[e*U + mem*16 + c];
    short hi = f2bf(v);
    short lo = f2bf(v - bf2f(hi));
    sK0[0][c][e] = hi; sK0[1][c][e] = lo;
  }
  for (int i = tid; i < 16*T; i += 128){
    int r = i / T, t = i - r*T;
    sTok[r][t] = tokens[(cl*16 + r)*T + t];
  }
  if (tid < 16){ sB0[tid] = b0[mem*16 + tid]; sB1[tid] = b1[mem*16 + tid]; }
  __syncthreads();

  // -------- L2-flag replay hygiene: atomic-zero own flag, MALL rendezvous --
  // Atomic swap executes at the XCD L2 and overwrites any stale dirty line
  // left by a previous graph replay (memset does not reach other-XCD L2s).
  // The rendezvous (R9-proven MALL primitives, separate memset-zeroed word)
  // guarantees ALL zero-swaps are done before anyone polls an L2 flag.
  if (tid == 0){
    int z = 0;
    asm volatile("global_atomic_swap %0, %1, off" :: "v"(myFlagL), "v"(z) : "memory");
    asm volatile("s_waitcnt vmcnt(0)" ::: "memory");
    STORE_RLX(myFlagR, 1);
  }
  if (w == 0){ while (__any(LOAD_RLX(pollAddrR) < 1)) {} }
  __syncthreads();

  // post: drain data atomics to L2 (ack == L2 execution), then lane0 swaps
  // the round id into the L2 flag and mirrors it to the R9 MALL flag.
  auto post = [&](int val){
    asm volatile("s_waitcnt vmcnt(0)" ::: "memory");
    if (lane == 0){
      asm volatile("global_atomic_swap %0, %1, off" :: "v"(myFlagL), "v"(val) : "memory");
      STORE_RLX(myFlagM, val);
    }
  };
  // poll (called by wave0 only; the following barrier releases wave1):
  // bounded fast spin of atomic-or-0 with return (executes at L2, reads the
  // fresh line, never L1-served). On timeout, fall back to the R9-proven
  // MALL spin -> termination by construction.
  auto pollFlags = [&](int target){
    int z = 0;
    #pragma unroll 1
    for (int it = 0; it < 48; ++it){
      int v;
      asm volatile("global_atomic_or %0, %1, %2, off sc0\n\t"
                   "s_waitcnt vmcnt(0)"
                   : "=v"(v) : "v"(pollAddrL), "v"(z) : "memory");
      if (!__any(v < target)) return;
    }
    while (__any(LOAD_RLX(pollAddrM) < target)) {}
  };
  // L2 gather: 16x dwordx4 sc0 (bypass L1, hit XCD-shared L2), then unpack.
  auto gather = [&](const unsigned* srcPk){
    const uint4* s = (const uint4*)(srcPk + cl*16*U);   // 2048 uint4 = 32 KB
    uint4 r[16];
    #pragma unroll
    for (int j = 0; j < 16; ++j)
      asm volatile("global_load_dwordx4 %0, %1, off sc0"
                   : "=v"(r[j]) : "v"(&s[j*128 + tid]));
    asm volatile("s_waitcnt vmcnt(0)" ::: "memory");
    #pragma unroll
    for (int j = 0; j < 16; ++j){
      int i = j*128 + tid, row = i >> 7, c = (i & 127) * 4;
      unsigned h0 = (r[j].x >> 16)     | (r[j].y & 0xffff0000u);
      unsigned h1 = (r[j].z >> 16)     | (r[j].w & 0xffff0000u);
      unsigned l0 = (r[j].x & 0xffffu) | (r[j].y << 16);
      unsigned l1 = (r[j].z & 0xffffu) | (r[j].w << 16);
      uint2 hh; hh.x = h0; hh.y = h1;
      uint2 ll; ll.x = l0; ll.y = l1;
      *(uint2*)&sH[0][row][c] = hh;
      *(uint2*)&sH[1][row][c] = ll;
    }
  };

  const f32x4 zero4 = {0.f, 0.f, 0.f, 0.f};

  // ---------------- recurrence ----------------
  for (int t = 0; t < T; ++t){
    // stage emb rows into regs early (independent of exchange)
    float ev[13];
    #pragma unroll
    for (int p = 0; p < 13; ++p){
      int i = tid + p*128;
      ev[p] = (i < 16*E) ? emb[sTok[i/E][t]*E + (i % E)] : 0.f;
    }
    if (t > 0 && w == 0) pollFlags(2*t);   // all round-B(t-1) posts
    __syncthreads();
    if (t > 0) gather(hPk);
    #pragma unroll
    for (int p = 0; p < 13; ++p){
      int i = tid + p*128;
      if (i < 16*E){
        int row = i / E, e = i % E;
        short hi = f2bf(ev[p]);
        short lo = f2bf(ev[p] - bf2f(hi));
        sE[0][row][e] = hi; sE[1][row][e] = lo;
      }
    }
    __syncthreads();

    // ---- round A: wave0: h0 = tanh(x@k0 + h@rk0 + b0); wave1: h@rk1 partial
    f32x4 z1a = zero4, z1b = zero4, z1c = zero4, z1d = zero4;
    if (w == 0){
      f32x4 za = zero4, zb = zero4, zc = zero4, zd = zero4;
      #pragma unroll
      for (int kk = 0; kk < 4; ++kk){
        short8 ah = *(const short8*)&sE[0][m][kk*32 + q*8];
        short8 al = *(const short8*)&sE[1][m][kk*32 + q*8];
        short8 bh = *(const short8*)&sK0[0][m][kk*32 + q*8];
        short8 bl = *(const short8*)&sK0[1][m][kk*32 + q*8];
        za = MFMA16(ah, bh, za); zb = MFMA16(al, bh, zb);
        zc = MFMA16(ah, bl, zc); zd = MFMA16(al, bl, zd);
      }
      if (t > 0){
        #pragma unroll
        for (int kk = 0; kk < 16; ++kk){
          short8 ah = *(const short8*)&sH[0][m][kk*32 + q*8];
          short8 al = *(const short8*)&sH[1][m][kk*32 + q*8];
          short8 bh = *(const short8*)&sW[0][m][kk*32 + q*8];
          short8 bl = *(const short8*)&sW[1][m][kk*32 + q*8];
          za = MFMA16(ah, bh, za); zb = MFMA16(al, bh, zb);
          zc = MFMA16(ah, bl, zc); zd = MFMA16(al, bl, zd);
        }
      }
      f32x4 z = za; z += zb; z += zc; z += zd;
      #pragma unroll
      for (int r = 0; r < 4; ++r){
        float h0v = fast_tanh(z[r] + sB0[m]);
        short hi = f2bf(h0v);
        short lo = f2bf(h0v - bf2f(hi));
        int gr = cl*16 + q*4 + r, gc = mem*16 + m;
        unsigned pk = ((unsigned)(unsigned short)hi << 16) | (unsigned short)lo;
        unsigned* p = &h0Pk[gr*U + gc];
        asm volatile("global_atomic_swap %0, %1, off" :: "v"(p), "v"(pk) : "memory");
      }
      post(2*t + 1);                       // h0 ready (this member)
    } else {
      if (t > 0){
        #pragma unroll
        for (int kk = 0; kk < 16; ++kk){
          short8 ah = *(const short8*)&sH[0][m][kk*32 + q*8];
          short8 al = *(const short8*)&sH[1][m][kk*32 + q*8];
          short8 bh = *(const short8*)&sW[2][m][kk*32 + q*8];
          short8 bl = *(const short8*)&sW[3][m][kk*32 + q*8];
          z1a = MFMA16(ah, bh, z1a); z1b = MFMA16(al, bh, z1b);
          z1c = MFMA16(ah, bl, z1c); z1d = MFMA16(al, bl, z1d);
        }
      }
    }

    // ---- round B: h1 = tanh(h0@k1 + h@rk1 + b1)
    if (w == 0) pollFlags(2*t + 1);        // all round-A posts
    __syncthreads();                       // releases wave1; round-A sH reads retired
    gather(h0Pk);
    __syncthreads();
    if (w == 1){
      f32x4 za = zero4, zb = zero4, zc = zero4, zd = zero4;
      #pragma unroll
      for (int kk = 0; kk < 16; ++kk){
        short8 ah = *(const short8*)&sH[0][m][kk*32 + q*8];
        short8 al = *(const short8*)&sH[1][m][kk*32 + q*8];
        short8 bh = *(const short8*)&sW[4][m][kk*32 + q*8];
        short8 bl = *(const short8*)&sW[5][m][kk*32 + q*8];
        za = MFMA16(ah, bh, za); zb = MFMA16(al, bh, zb);
        zc = MFMA16(ah, bl, zc); zd = MFMA16(al, bl, zd);
      }
      f32x4 z = za; z += zb; z += zc; z += zd;
      z += z1a; z += z1b; z += z1c; z += z1d;
      #pragma unroll
      for (int r = 0; r < 4; ++r){
        float h1v = fast_tanh(z[r] + sB1[m]);
        short hi = f2bf(h1v);
        short lo = f2bf(h1v - bf2f(hi));
        int gr = cl*16 + q*4 + r, gc = mem*16 + m;
        unsigned pk = ((unsigned)(unsigned short)hi << 16) | (unsigned short)lo;
        unsigned* p = &hPk[gr*U + gc];
        asm volatile("global_atomic_swap %0, %1, off" :: "v"(p), "v"(pk) : "memory");
      }
      post(2*t + 2);                       // h1 = h(t) ready (this member)
    }
    // no trailing barrier: loop-top poll+barrier aligns waves
  }

  // ---------------- epilogue: logits = h@wd + bd ; sigmoid ----------------
  if (mem == 0){
    if (w == 0) pollFlags(2*T);
    __syncthreads();
    gather(hPk);
    __syncthreads();
    {
      int row = tid >> 3, seg = tid & 7;
      float acc = 0.f;
      for (int u = seg*64; u < seg*64 + 64; ++u){
        float hv = bf2f(sH[0][row][u]) + bf2f(sH[1][row][u]);
        acc += hv * wd[u];
      }
      sRed[row][seg] = acc;
    }
    __syncthreads();
    if (tid < 16){
      float s = bd[0];
      #pragma unroll
      for (int j = 0; j < 8; ++j) s += sRed[tid][j];
      out[cl*16 + tid] = 1.f / (1.f + __expf(-s));
    }
  }

  // replay hygiene: flush/invalidate this XCD's L2 exchange+flag lines so no
  // stale dirty copies survive into the next graph replay (one-time cost)
  __threadfence();
}

extern "C" void kernel_launch(void* const* d_in, const int* in_sizes, int n_in,
                              void* d_out, int out_size, void* d_ws, size_t ws_size,
                              hipStream_t stream) {
  const int*   tokens = (const int*)  d_in[0];
  const float* emb    = (const float*)d_in[1];
  const float* k0     = (const float*)d_in[2];
  const float* rk0    = (const float*)d_in[3];
  const float* b0     = (const float*)d_in[4];
  const float* k1     = (const float*)d_in[5];
  const float* rk1    = (const float*)d_in[6];
  const float* b1     = (const float*)d_in[7];
  const float* wd     = (const float*)d_in[8];
  const float* bd     = (const float*)d_in[9];

  // Zero registration counters + all flag regions (0xAA poison breaks
  // monotonic arith). regCnt@512, flagsL@1024, flagsR@5120, flagsM@8192..16384;
  // exchange data starts at 16384 (no memset needed — fully rewritten at t=0).
  hipMemsetAsync(d_ws, 0, 16384, stream);

  hipLaunchKernelGGL(rnn_kernel, dim3(256), dim3(128), 0, stream,
                     tokens, emb, k0, rk0, b0, k1, rk1, b1, wd, bd,
                     (float*)d_out, (char*)d_ws);
}

// Round 5
// 625.909 us; speedup vs baseline: 2.4198x; 2.4198x over previous
//
#include <hip/hip_runtime.h>

// MyRNN: B=128, T=80, E=100, V=10000, U=512
// 8 clusters x 32 member-blocks, formed DYNAMICALLY by physical XCD
// (s_getreg HW_REG_XCC_ID + atomic slot grab): with 156KB LDS -> 1 block/CU,
// grid 256 fills all CUs, so each XCD hosts exactly 32 blocks -> a cluster's
// members share one L2 BY CONSTRUCTION (G16-sound, no mapping assumption).
// Cluster c owns batch rows [16c,16c+16); member m owns cols [16m,16m+16) of
// rk0/rk1/k1 (stationary in LDS, hi/lo bf16 split).
// R1-R6: protocol variants on MALL data path pinned at 5.5-7us/exchange.
// R7 (745us): data path on XCD L2 (plain stores + sc0 dwordx4 gathers);
//   protocol on MALL single atomic counter (32 serialized RMWs).
// R9 (588us): per-member MALL flag words -> parallel posts, wave-par poll.
// R8/R10: plain-store L2 flags not promptly visible to sc0 polls (store-side
//   commit lag) -> hang / always-timeout. HW fact.
// R11 (1445us, WRITE_SIZE 2MB->149MB): gfx950 global atomics execute at the
//   MEMORY-SIDE coherence point and write through to HBM -- never XCD-L2-
//   local, regardless of sc flags. HW fact. L2-local signaling is DEAD;
//   the MALL round trip (~1us) is this structure's protocol floor.
// R12: revert to R9 exactly, plus three provable-safe chain shavings:
//   (a) wave1 stages sE[t] (emb load+f2bf+LDS store) WHILE wave0 polls --
//       safe: wave0's last sE[t-1] read retires before the round-B barriers
//       of t-1, and wave1 never reads sE;
//   (b) wave0-only polling (R11-validated structure), barrier releases w1:
//       halves MALL spin pressure;
//   (c) flag stride 32B -> 128B: one member per cache line, no line-ownership
//       serialization between adjacent members' posts.
//   Everything else (data stores, vmcnt(0)->post order, gather, barriers,
//   monotonic round-id flags 2t+1/2t+2, end __threadfence) is R9-proven.

typedef __attribute__((ext_vector_type(8))) short short8;
typedef __attribute__((ext_vector_type(4))) float f32x4;

#define MFMA16(a,b,c) __builtin_amdgcn_mfma_f32_16x16x32_bf16(a,b,c,0,0,0)
#define LOAD_RLX(p)    __hip_atomic_load((p), __ATOMIC_RELAXED, __HIP_MEMORY_SCOPE_AGENT)
#define STORE_RLX(p,v) __hip_atomic_store((p), (v), __ATOMIC_RELAXED, __HIP_MEMORY_SCOPE_AGENT)
#define ADD_RLX(p,v)   __hip_atomic_fetch_add((p), (v), __ATOMIC_RELAXED, __HIP_MEMORY_SCOPE_AGENT)

__device__ __forceinline__ short f2bf(float v){
  unsigned u = __float_as_uint(v);
  u = (u + 0x7fffu + ((u >> 16) & 1u)) >> 16;   // RNE to bf16
  return (short)u;
}
__device__ __forceinline__ float bf2f(short s){
  return __uint_as_float(((unsigned)(unsigned short)s) << 16);
}
__device__ __forceinline__ float fast_tanh(float x){
  x = fminf(15.f, fmaxf(-15.f, x));
  float e = __expf(2.f * x);
  return (e - 1.f) * __builtin_amdgcn_rcpf(e + 1.f);
}

__launch_bounds__(128, 1)
__global__ void rnn_kernel(const int* __restrict__ tokens,
                           const float* __restrict__ emb,
                           const float* __restrict__ k0,
                           const float* __restrict__ rk0,
                           const float* __restrict__ b0,
                           const float* __restrict__ k1,
                           const float* __restrict__ rk1,
                           const float* __restrict__ b1,
                           const float* __restrict__ wd,
                           const float* __restrict__ bd,
                           float* __restrict__ out,
                           char* __restrict__ ws)
{
  constexpr int T = 80, E = 100, U = 512;
  const int tid  = threadIdx.x;
  const int w    = tid >> 6;          // wave id (0/1)
  const int lane = tid & 63;
  const int m    = lane & 15;         // row (A) / col (B,C)
  const int q    = lane >> 4;         // quad 0..3

  __shared__ __align__(16) short sW[6][16][520];   // rk0 hi/lo, rk1 hi/lo, k1 hi/lo : [col][k]
  __shared__ __align__(16) short sH[2][16][520];   // h / h0 staging hi,lo : [row][k]
  __shared__ __align__(16) short sE[2][16][136];   // emb rows hi,lo (K padded to 128 w/ zeros)
  __shared__ __align__(16) short sK0[2][16][136];  // k0 slice hi,lo : [col][k] (padded)
  __shared__ int   sTok[16][80];
  __shared__ float sB0[16], sB1[16];
  __shared__ float sRed[16][8];
  __shared__ int   sReg[2];

  // ws layout: regCnt@512 (MALL), flags@4096 (256 x 128B line-isolated, MALL),
  // exchange data @ 40960 (memset span 40960 covers all flag regions).
  int*      regCnt = (int*)(ws + 512);             // 8 registration counters, 64B stride
  int*      flags  = (int*)(ws + 4096);            // [cl*32+mem] round-id flags, 128B stride
  unsigned* hPk    = (unsigned*)(ws + 40960);      // h1 packed (hi<<16|lo), [128][512]
  unsigned* h0Pk   = hPk + 128*U;                  // h0 packed

  // -------- dynamic cluster formation: cluster id = physical XCD --------
  int xcc;
  asm volatile("s_getreg_b32 %0, hwreg(HW_REG_XCC_ID)" : "=s"(xcc));
  if (tid == 0){
    int slot = ADD_RLX(regCnt + (xcc & 7)*16, 1);  // 0..31 within this XCD
    sReg[0] = xcc & 7;
    sReg[1] = slot;
  }
  __syncthreads();
  const int cl  = sReg[0];
  const int mem = sReg[1];
  int* const myFlag   = flags + (cl*32 + mem)*32;         // 128B stride
  int* const pollAddr = flags + (cl*32 + (lane & 31))*32; // lane -> member flag

  // ---------------- prologue: stationary weights -> LDS ----------------
  const float* mats[3] = { rk0, rk1, k1 };
  for (int mi = 0; mi < 3; ++mi){
    const float* G = mats[mi];
    for (int i = tid; i < 16*U; i += 128){
      int k = i >> 4, c = i & 15;
      float v  = G[k*U + mem*16 + c];
      short hi = f2bf(v);
      short lo = f2bf(v - bf2f(hi));
      sW[2*mi+0][c][k] = hi;
      sW[2*mi+1][c][k] = lo;
    }
  }
  for (int i = tid; i < 2*16*136; i += 128){ ((short*)sE)[i] = 0; ((short*)sK0)[i] = 0; }
  __syncthreads();
  for (int i = tid; i < 16*E; i += 128){
    int e = i >> 4, c = i & 15;
    float v  = k0[e*U + mem*16 + c];
    short hi = f2bf(v);
    short lo = f2bf(v - bf2f(hi));
    sK0[0][c][e] = hi; sK0[1][c][e] = lo;
  }
  for (int i = tid; i < 16*T; i += 128){
    int r = i / T, t = i - r*T;
    sTok[r][t] = tokens[(cl*16 + r)*T + t];
  }
  if (tid < 16){ sB0[tid] = b0[mem*16 + tid]; sB1[tid] = b1[mem*16 + tid]; }
  __syncthreads();

  // post: drain data stores to L2 (vmcnt ack), then lane0 agent-stores the
  // round id to this member's line-isolated MALL flag word (R9-proven path).
  auto post = [&](int val){
    asm volatile("s_waitcnt vmcnt(0)" ::: "memory");
    if (lane == 0) STORE_RLX(myFlag, val);
  };
  // wave-parallel poll (called by WAVE0 ONLY; following barrier releases w1):
  // lanes each watch one member's flag via agent-scope relaxed loads.
  auto pollFlags = [&](int target){
    while (__any(LOAD_RLX(pollAddr) < target)) {}
  };
  // L2 gather: 16x dwordx4 sc0 (bypass L1), then unpack into sH hi/lo.
  auto gather = [&](const unsigned* srcPk){
    const uint4* s = (const uint4*)(srcPk + cl*16*U);   // 2048 uint4 = 32 KB
    uint4 r[16];
    #pragma unroll
    for (int j = 0; j < 16; ++j)
      asm volatile("global_load_dwordx4 %0, %1, off sc0"
                   : "=v"(r[j]) : "v"(&s[j*128 + tid]));
    asm volatile("s_waitcnt vmcnt(0)" ::: "memory");
    #pragma unroll
    for (int j = 0; j < 16; ++j){
      int i = j*128 + tid, row = i >> 7, c = (i & 127) * 4;
      unsigned h0 = (r[j].x >> 16)     | (r[j].y & 0xffff0000u);
      unsigned h1 = (r[j].z >> 16)     | (r[j].w & 0xffff0000u);
      unsigned l0 = (r[j].x & 0xffffu) | (r[j].y << 16);
      unsigned l1 = (r[j].z & 0xffffu) | (r[j].w << 16);
      uint2 hh; hh.x = h0; hh.y = h1;
      uint2 ll; ll.x = l0; ll.y = l1;
      *(uint2*)&sH[0][row][c] = hh;
      *(uint2*)&sH[1][row][c] = ll;
    }
  };

  const f32x4 zero4 = {0.f, 0.f, 0.f, 0.f};

  // ---------------- recurrence ----------------
  for (int t = 0; t < T; ++t){
    // (a) wave1 stages sE[t] OFF the critical path while wave0 polls.
    // Safe: wave0's last sE[t-1] read retired before the round-B barriers
    // of t-1 (which wave1 passed to get here); wave1 never reads sE.
    if (w == 1){
      float ev[25];
      #pragma unroll
      for (int p = 0; p < 25; ++p){
        int i = lane + p*64;                 // 25*64 = 1600 = 16*E exactly
        ev[p] = emb[sTok[i/E][t]*E + (i % E)];
      }
      #pragma unroll
      for (int p = 0; p < 25; ++p){
        int i = lane + p*64;
        int row = i / E, e = i % E;
        short hi = f2bf(ev[p]);
        short lo = f2bf(ev[p] - bf2f(hi));
        sE[0][row][e] = hi; sE[1][row][e] = lo;
      }
    } else {
      if (t > 0) pollFlags(2*t);             // all round-B(t-1) posts
    }
    __syncthreads();
    if (t > 0) gather(hPk);
    __syncthreads();

    // ---- round A: wave0: h0 = tanh(x@k0 + h@rk0 + b0); wave1: h@rk1 partial
    f32x4 z1a = zero4, z1b = zero4, z1c = zero4, z1d = zero4;
    if (w == 0){
      f32x4 za = zero4, zb = zero4, zc = zero4, zd = zero4;
      #pragma unroll
      for (int kk = 0; kk < 4; ++kk){
        short8 ah = *(const short8*)&sE[0][m][kk*32 + q*8];
        short8 al = *(const short8*)&sE[1][m][kk*32 + q*8];
        short8 bh = *(const short8*)&sK0[0][m][kk*32 + q*8];
        short8 bl = *(const short8*)&sK0[1][m][kk*32 + q*8];
        za = MFMA16(ah, bh, za); zb = MFMA16(al, bh, zb);
        zc = MFMA16(ah, bl, zc); zd = MFMA16(al, bl, zd);
      }
      if (t > 0){
        #pragma unroll
        for (int kk = 0; kk < 16; ++kk){
          short8 ah = *(const short8*)&sH[0][m][kk*32 + q*8];
          short8 al = *(const short8*)&sH[1][m][kk*32 + q*8];
          short8 bh = *(const short8*)&sW[0][m][kk*32 + q*8];
          short8 bl = *(const short8*)&sW[1][m][kk*32 + q*8];
          za = MFMA16(ah, bh, za); zb = MFMA16(al, bh, zb);
          zc = MFMA16(ah, bl, zc); zd = MFMA16(al, bl, zd);
        }
      }
      f32x4 z = za; z += zb; z += zc; z += zd;
      #pragma unroll
      for (int r = 0; r < 4; ++r){
        float h0v = fast_tanh(z[r] + sB0[m]);
        short hi = f2bf(h0v);
        short lo = f2bf(h0v - bf2f(hi));
        int gr = cl*16 + q*4 + r, gc = mem*16 + m;
        unsigned pk = ((unsigned)(unsigned short)hi << 16) | (unsigned short)lo;
        h0Pk[gr*U + gc] = pk;              // plain store -> write-through to XCD L2
      }
      post(2*t + 1);                       // h0 ready (this member)
    } else {
      if (t > 0){
        #pragma unroll
        for (int kk = 0; kk < 16; ++kk){
          short8 ah = *(const short8*)&sH[0][m][kk*32 + q*8];
          short8 al = *(const short8*)&sH[1][m][kk*32 + q*8];
          short8 bh = *(const short8*)&sW[2][m][kk*32 + q*8];
          short8 bl = *(const short8*)&sW[3][m][kk*32 + q*8];
          z1a = MFMA16(ah, bh, z1a); z1b = MFMA16(al, bh, z1b);
          z1c = MFMA16(ah, bl, z1c); z1d = MFMA16(al, bl, z1d);
        }
      }
    }

    // ---- round B: h1 = tanh(h0@k1 + h@rk1 + b1)
    if (w == 0) pollFlags(2*t + 1);        // all round-A posts (w1 finishing z1)
    __syncthreads();                       // releases w1; round-A sH reads retired
    gather(h0Pk);
    __syncthreads();
    if (w == 1){
      f32x4 za = zero4, zb = zero4, zc = zero4, zd = zero4;
      #pragma unroll
      for (int kk = 0; kk < 16; ++kk){
        short8 ah = *(const short8*)&sH[0][m][kk*32 + q*8];
        short8 al = *(const short8*)&sH[1][m][kk*32 + q*8];
        short8 bh = *(const short8*)&sW[4][m][kk*32 + q*8];
        short8 bl = *(const short8*)&sW[5][m][kk*32 + q*8];
        za = MFMA16(ah, bh, za); zb = MFMA16(al, bh, zb);
        zc = MFMA16(ah, bl, zc); zd = MFMA16(al, bl, zd);
      }
      f32x4 z = za; z += zb; z += zc; z += zd;
      z += z1a; z += z1b; z += z1c; z += z1d;
      #pragma unroll
      for (int r = 0; r < 4; ++r){
        float h1v = fast_tanh(z[r] + sB1[m]);
        short hi = f2bf(h1v);
        short lo = f2bf(h1v - bf2f(hi));
        int gr = cl*16 + q*4 + r, gc = mem*16 + m;
        unsigned pk = ((unsigned)(unsigned short)hi << 16) | (unsigned short)lo;
        hPk[gr*U + gc] = pk;               // plain store -> XCD L2
      }
      post(2*t + 2);                       // h1 = h(t) ready (this member)
    }
    // no trailing barrier: loop-top poll+barrier aligns waves
  }

  // ---------------- epilogue: logits = h@wd + bd ; sigmoid ----------------
  if (mem == 0){
    if (w == 0) pollFlags(2*T);
    __syncthreads();
    gather(hPk);
    __syncthreads();
    {
      int row = tid >> 3, seg = tid & 7;
      float acc = 0.f;
      for (int u = seg*64; u < seg*64 + 64; ++u){
        float hv = bf2f(sH[0][row][u]) + bf2f(sH[1][row][u]);
        acc += hv * wd[u];
      }
      sRed[row][seg] = acc;
    }
    __syncthreads();
    if (tid < 16){
      float s = bd[0];
      #pragma unroll
      for (int j = 0; j < 8; ++j) s += sRed[tid][j];
      out[cl*16 + tid] = 1.f / (1.f + __expf(-s));
    }
  }

  // replay hygiene: flush/invalidate this XCD's L2 exchange lines so no stale
  // dirty copies survive into the next graph replay (one-time cost)
  __threadfence();
}

extern "C" void kernel_launch(void* const* d_in, const int* in_sizes, int n_in,
                              void* d_out, int out_size, void* d_ws, size_t ws_size,
                              hipStream_t stream) {
  const int*   tokens = (const int*)  d_in[0];
  const float* emb    = (const float*)d_in[1];
  const float* k0     = (const float*)d_in[2];
  const float* rk0    = (const float*)d_in[3];
  const float* b0     = (const float*)d_in[4];
  const float* k1     = (const float*)d_in[5];
  const float* rk1    = (const float*)d_in[6];
  const float* b1     = (const float*)d_in[7];
  const float* wd     = (const float*)d_in[8];
  const float* bd     = (const float*)d_in[9];

  // Zero registration counters + flag region (0xAA poison breaks monotonic
  // arith). regCnt@512, flags@4096..36864; exchange data starts at 40960
  // (no memset needed there — fully rewritten at t=0 before first gather).
  hipMemsetAsync(d_ws, 0, 40960, stream);

  hipLaunchKernelGGL(rnn_kernel, dim3(256), dim3(128), 0, stream,
                     tokens, emb, k0, rk0, b0, k1, rk1, b1, wd, bd,
                     (float*)d_out, (char*)d_ws);
}